// Round 2
// baseline (376.153 us; speedup 1.0000x reference)
//
#include <hip/hip_runtime.h>
#include <math.h>

#define B_ 64
#define N_ 16384
#define D_ 64
#define K_ 8
#define SCALE 0.125f          // 1/sqrt(64)
#define LN_EPS 1e-5f
#define CHUNKS 8
#define ROWS_PER_CHUNK (N_ / CHUNKS)   // 2048
#define TILES (ROWS_PER_CHUNK / 256)   // 8
#define REC 528               // record: 512 Y + 8 S + 8 t1

__device__ __forceinline__ float wsum64(float v) {
#pragma unroll
  for (int m = 1; m < 64; m <<= 1) v += __shfl_xor(v, m);
  return v;
}

// slots = mu + sigma * noise   (32768 elems)
__global__ void init_slots(const float* __restrict__ noise, const float* __restrict__ mu,
                           const float* __restrict__ sg, float* __restrict__ slots) {
  int i = blockIdx.x * blockDim.x + threadIdx.x;
  int d = i & 63;
  slots[i] = mu[d] + sg[d] * noise[i];
}

// Per (b,kk): q = LN(slots; ln_slots)@wq + bq ; fold through wk and input-LN affine.
__global__ __launch_bounds__(64) void prep_q(
    const float* __restrict__ slots,
    const float* __restrict__ lnsw, const float* __restrict__ lnsb,
    const float* __restrict__ wq, const float* __restrict__ bq,
    const float* __restrict__ wk, const float* __restrict__ bk,
    const float* __restrict__ lniw, const float* __restrict__ lnib,
    float* __restrict__ qprep) {
  const int bk_i = blockIdx.x;            // b*8+kk
  const int b = bk_i >> 3, kk = bk_i & 7;
  const int d = threadIdx.x;
  __shared__ float xs[64], qsh[64], wkl[64 * 65];
  for (int i = 0; i < 64; ++i) wkl[i * 65 + d] = wk[i * 64 + d];
  float s = slots[bk_i * 64 + d];
  float m = wsum64(s) * (1.f / 64.f);
  float df = s - m;
  float var = wsum64(df * df) * (1.f / 64.f);
  float r = 1.f / sqrtf(var + LN_EPS);
  xs[d] = df * r * lnsw[d] + lnsb[d];
  __syncthreads();
  float q = bq[d];
  for (int c = 0; c < 64; ++c) q += xs[c] * wq[c * 64 + d];
  qsh[d] = q;
  __syncthreads();
  float qp = 0.f, c0 = 0.f;
  for (int dd = 0; dd < 64; ++dd) {
    float qd = qsh[dd];
    qp += wkl[d * 65 + dd] * qd;
    c0 += qd * bk[dd];
  }
  float qw = qp * lniw[d] * SCALE;
  float As = wsum64(qw);
  float Bp = wsum64(qp * lnib[d]);
  float Bc = (Bp + c0) * SCALE;
  float* rec = qprep + b * REC;
  rec[d * 8 + kk] = qw;                   // qwT[c][kk]
  if (d == 0) { rec[512 + kk] = As; rec[520 + kk] = Bc; }
}

// Main streaming pass: grid = B*CHUNKS = 512 blocks x 256 threads (2 blocks/CU).
// Per tile (256 rows): phase A in registers (qw via scalar loads), full-tile
// swizzled LDS staging, register prefetch of next tile, vectorized phase B.
__global__ __launch_bounds__(256, 2) void attn_pass(
    const float* __restrict__ inp, const float* __restrict__ qprep,
    float* __restrict__ part) {
  __shared__ __align__(16) float xrow[256 * 68];   // 69632 B, swizzled float4 columns
  __shared__ float2 aw[4 * 257];                   // 8224 B
  __shared__ float redST[64];
  const int tid = threadIdx.x;
  const int b = blockIdx.x >> 3, chunk = blockIdx.x & 7;
  const int p = tid & 3, dq = (tid >> 2) & 15, w = tid >> 6;
  const float* __restrict__ qp = qprep + b * REC;  // wave-uniform -> s_load
  const float* srcbase = inp + ((size_t)b * N_ + (size_t)chunk * ROWS_PER_CHUNK) * D_;
  float4 x[16];
  {
    const float4* s = reinterpret_cast<const float4*>(srcbase + (size_t)tid * D_);
#pragma unroll
    for (int j = 0; j < 16; ++j) x[j] = s[j];
  }
  float Ya[8] = {0.f, 0.f, 0.f, 0.f, 0.f, 0.f, 0.f, 0.f};
  float sS[8] = {0.f, 0.f, 0.f, 0.f, 0.f, 0.f, 0.f, 0.f};
  float sT[8] = {0.f, 0.f, 0.f, 0.f, 0.f, 0.f, 0.f, 0.f};
  for (int t = 0; t < TILES; ++t) {
    // ---- phase A: per-row stats + 8 dots + softmax (registers + s_loads) ----
    float sum = 0.f, sq = 0.f;
    float l[8] = {0.f, 0.f, 0.f, 0.f, 0.f, 0.f, 0.f, 0.f};
#pragma unroll
    for (int j = 0; j < 16; ++j) {
      float xc[4] = {x[j].x, x[j].y, x[j].z, x[j].w};
#pragma unroll
      for (int e = 0; e < 4; ++e) {
        const int c = j * 4 + e;
        const float v = xc[e];
        sum += v; sq += v * v;
#pragma unroll
        for (int kq = 0; kq < 8; ++kq) l[kq] += qp[c * 8 + kq] * v;
      }
    }
    const float m = sum * (1.f / 64.f);
    const float var = sq * (1.f / 64.f) - m * m;
    const float r = 1.f / sqrtf(var + LN_EPS);
    const float mr = m * r;
    float lmax = -1e30f;
#pragma unroll
    for (int kq = 0; kq < 8; ++kq) {
      l[kq] = r * l[kq] - mr * qp[512 + kq] + qp[520 + kq];
      lmax = fmaxf(lmax, l[kq]);
    }
    float es = 0.f;
#pragma unroll
    for (int kq = 0; kq < 8; ++kq) { l[kq] = __expf(l[kq] - lmax); es += l[kq]; }
    const float inv = 1.f / es;
#pragma unroll
    for (int kq = 0; kq < 8; ++kq) {
      l[kq] *= inv;                 // a[kq]
      sS[kq] += l[kq];
      sT[kq] += l[kq] * mr;
    }
    // a*r pairs -> LDS (b64, 2-way = free)
#pragma unroll
    for (int pp = 0; pp < 4; ++pp) {
      float2 v2; v2.x = l[2 * pp] * r; v2.y = l[2 * pp + 1] * r;
      aw[pp * 257 + tid] = v2;
    }
    // ---- stage full tile, swizzled cols: phys = (j + row>>3) & 15 (conflict-free) ----
    {
      float* dst = &xrow[tid * 68];
      const int rs = tid >> 3;
#pragma unroll
      for (int j = 0; j < 16; ++j) {
        const int cs = (j + rs) & 15;
        *reinterpret_cast<float4*>(dst + cs * 4) = x[j];
      }
    }
    // ---- prefetch next tile into freed x regs (overlaps phase B) ----
    if (t + 1 < TILES) {
      const float4* s = reinterpret_cast<const float4*>(srcbase + (size_t)((t + 1) * 256 + tid) * D_);
#pragma unroll
      for (int j = 0; j < 16; ++j) x[j] = s[j];
    }
    __syncthreads();
    // ---- phase B: wave w owns rows w*64..w*64+63; thread (p,dq) -> kk=2p,2p+1, d=dq*4..+3 ----
#pragma unroll 4
    for (int i = 0; i < 64; ++i) {
      const int nl = w * 64 + i;
      const float2 a2 = aw[p * 257 + nl];
      const float4 xv = *reinterpret_cast<const float4*>(
          &xrow[nl * 68 + (((dq + (nl >> 3)) & 15) << 2)]);
      Ya[0] += a2.x * xv.x; Ya[1] += a2.x * xv.y; Ya[2] += a2.x * xv.z; Ya[3] += a2.x * xv.w;
      Ya[4] += a2.y * xv.x; Ya[5] += a2.y * xv.y; Ya[6] += a2.y * xv.z; Ya[7] += a2.y * xv.w;
    }
    __syncthreads();
  }
  // ---- epilogue: one-time reductions ----
#pragma unroll
  for (int kq = 0; kq < 8; ++kq) { sS[kq] = wsum64(sS[kq]); sT[kq] = wsum64(sT[kq]); }
  if ((tid & 63) == 0) {
#pragma unroll
    for (int i = 0; i < 8; ++i) { redST[w * 16 + i] = sS[i]; redST[w * 16 + 8 + i] = sT[i]; }
  }
  float* yred = xrow;   // reuse (all phase-B reads done at last barrier)
  *reinterpret_cast<float4*>(&yred[tid * 12]) = make_float4(Ya[0], Ya[1], Ya[2], Ya[3]);
  *reinterpret_cast<float4*>(&yred[tid * 12 + 4]) = make_float4(Ya[4], Ya[5], Ya[6], Ya[7]);
  __syncthreads();
  float* dst = part + (size_t)blockIdx.x * REC;
  for (int o = tid; o < 512; o += 256) {
    const int kq = o >> 6, dd = o & 63;
    const int pp = kq >> 1, kkl = kq & 1, dqq = dd >> 2, jj = dd & 3;
    float v = 0.f;
#pragma unroll
    for (int ww = 0; ww < 4; ++ww)
      v += yred[(ww * 64 + dqq * 4 + pp) * 12 + kkl * 4 + jj];
    dst[o] = v;
  }
  if (tid < 16)
    dst[512 + tid] = redST[tid] + redST[16 + tid] + redST[32 + tid] + redST[48 + tid];
}

// Fused: partial-reduce -> updates -> GRU -> LN -> MLP -> new slots -> q-prep(next).
// Per (b,kk) block, 256 threads: cq = tid>>6 splits 64-length sums 4-way.
__global__ __launch_bounds__(256) void slot_update(
    const float* __restrict__ part, const float* slots_in,
    const float* __restrict__ lniw, const float* __restrict__ lnib,
    const float* __restrict__ wv, const float* __restrict__ bv,
    const float* __restrict__ wih, const float* __restrict__ bih,
    const float* __restrict__ whh, const float* __restrict__ bhh,
    const float* __restrict__ lnfw, const float* __restrict__ lnfb,
    const float* __restrict__ w1, const float* __restrict__ b1,
    const float* __restrict__ w2, const float* __restrict__ b2,
    const float* __restrict__ lnsw, const float* __restrict__ lnsb,
    const float* __restrict__ wq, const float* __restrict__ bq,
    const float* __restrict__ wk, const float* __restrict__ bkv,
    float* slots_out, float* __restrict__ qprep, const int do_prep) {
  const int bk_i = blockIdx.x, b = bk_i >> 3, kk = bk_i & 7;
  const int tid = threadIdx.x, cq = tid >> 6, d = tid & 63;
  const int c0 = cq * 16;
  __shared__ float pA[4][68], pB[4][68], pC[4][68], pD[4][68];
  __shared__ float xsh[64], psh[64], ush[64], hsh[64], snsh[64], qsh[64];
  __shared__ float hid1[2][132];
  const float* pb = part + (size_t)(b * CHUNKS) * REC;
  float S = 0.f, T1 = 0.f;
#pragma unroll
  for (int ch = 0; ch < CHUNKS; ++ch) {          // uniform -> s_load
    S += pb[ch * REC + 512 + kk];
    T1 += pb[ch * REC + 520 + kk];
  }
  float y = 0.f;
#pragma unroll
  for (int cc = 0; cc < 2; ++cc)
    y += pb[(cq * 2 + cc) * REC + kk * 64 + d];
  pA[cq][d] = y;
  const float prev = slots_in[bk_i * 64 + d];
  if (cq == 0) psh[d] = prev;
  __syncthreads();                               // s1
  if (cq == 0) {
    const float Y = pA[0][d] + pA[1][d] + pA[2][d] + pA[3][d];
    xsh[d] = lniw[d] * (Y - T1) + lnib[d] * S;
  }
  __syncthreads();                               // s2
  {
    float up = 0.f, h0 = 0.f, h1 = 0.f, h2 = 0.f;
    for (int c = c0; c < c0 + 16; ++c) {
      const float xc = xsh[c], pc = psh[c];
      up += wv[c * 64 + d] * xc;
      h0 += pc * whh[c * 192 + d];
      h1 += pc * whh[c * 192 + 64 + d];
      h2 += pc * whh[c * 192 + 128 + d];
    }
    pA[cq][d] = up; pB[cq][d] = h0; pC[cq][d] = h1; pD[cq][d] = h2;
  }
  __syncthreads();                               // s3
  float hh0 = 0.f, hh1 = 0.f, hh2 = 0.f;
  if (cq == 0) {
    ush[d] = S * bv[d] + pA[0][d] + pA[1][d] + pA[2][d] + pA[3][d];
    hh0 = bhh[d] + pB[0][d] + pB[1][d] + pB[2][d] + pB[3][d];
    hh1 = bhh[64 + d] + pC[0][d] + pC[1][d] + pC[2][d] + pC[3][d];
    hh2 = bhh[128 + d] + pD[0][d] + pD[1][d] + pD[2][d] + pD[3][d];
  }
  __syncthreads();                               // s4
  {
    float g0 = 0.f, g1 = 0.f, g2 = 0.f;
    for (int c = c0; c < c0 + 16; ++c) {
      const float uc = ush[c];
      g0 += uc * wih[c * 192 + d];
      g1 += uc * wih[c * 192 + 64 + d];
      g2 += uc * wih[c * 192 + 128 + d];
    }
    pA[cq][d] = g0; pB[cq][d] = g1; pC[cq][d] = g2;
  }
  __syncthreads();                               // s5
  if (cq == 0) {
    const float gi0 = bih[d] + pA[0][d] + pA[1][d] + pA[2][d] + pA[3][d];
    const float gi1 = bih[64 + d] + pB[0][d] + pB[1][d] + pB[2][d] + pB[3][d];
    const float gi2 = bih[128 + d] + pC[0][d] + pC[1][d] + pC[2][d] + pC[3][d];
    const float rg = 1.f / (1.f + __expf(-(gi0 + hh0)));
    const float zg = 1.f / (1.f + __expf(-(gi1 + hh1)));
    const float ng = tanhf(gi2 + rg * hh2);
    const float sn = (1.f - zg) * ng + zg * prev;
    const float mm = wsum64(sn) * (1.f / 64.f);
    const float df = sn - mm;
    const float vv = wsum64(df * df) * (1.f / 64.f);
    const float rr = 1.f / sqrtf(vv + LN_EPS);
    snsh[d] = sn;
    hsh[d] = df * rr * lnfw[d] + lnfb[d];
  }
  __syncthreads();                               // s6
  {
    const int j = tid & 127, ch2 = tid >> 7;
    float a = 0.f;
    for (int c = ch2 * 32; c < ch2 * 32 + 32; ++c) a += hsh[c] * w1[c * 128 + j];
    hid1[ch2][j] = a;
  }
  __syncthreads();                               // s7
  {
    float o = 0.f;
    for (int j2 = cq * 32; j2 < cq * 32 + 32; ++j2) {
      const float hv = fmaxf(hid1[0][j2] + hid1[1][j2] + b1[j2], 0.f);
      o += hv * w2[j2 * 64 + d];
    }
    pA[cq][d] = o;
  }
  __syncthreads();                               // s8
  float news = 0.f;
  if (cq == 0) {
    news = snsh[d] + b2[d] + pA[0][d] + pA[1][d] + pA[2][d] + pA[3][d];
    slots_out[bk_i * 64 + d] = news;
  }
  if (!do_prep) return;
  // ---- fused q-prep for next iteration ----
  if (cq == 0) {
    const float mm = wsum64(news) * (1.f / 64.f);
    const float df = news - mm;
    const float vv = wsum64(df * df) * (1.f / 64.f);
    const float rr = 1.f / sqrtf(vv + LN_EPS);
    xsh[d] = df * rr * lnsw[d] + lnsb[d];
  }
  __syncthreads();                               // s9
  {
    float qpt = 0.f;
    for (int c = c0; c < c0 + 16; ++c) qpt += xsh[c] * wq[c * 64 + d];
    pB[cq][d] = qpt;
  }
  __syncthreads();                               // s10
  if (cq == 0) qsh[d] = bq[d] + pB[0][d] + pB[1][d] + pB[2][d] + pB[3][d];
  __syncthreads();                               // s11
  {
    float qq = 0.f;
    for (int dd2 = c0; dd2 < c0 + 16; ++dd2) qq += wk[d * 64 + dd2] * qsh[dd2];
    pC[cq][d] = qq;
  }
  __syncthreads();                               // s12
  if (cq == 0) {
    const float qpv = pC[0][d] + pC[1][d] + pC[2][d] + pC[3][d];
    const float c0v = wsum64(qsh[d] * bkv[d]);
    const float qw = qpv * lniw[d] * SCALE;
    const float As = wsum64(qw);
    const float Bp = wsum64(qpv * lnib[d]);
    const float Bc = (Bp + c0v) * SCALE;
    float* rec = qprep + b * REC;
    rec[d * 8 + kk] = qw;
    if (d == 0) { rec[512 + kk] = As; rec[520 + kk] = Bc; }
  }
}

extern "C" void kernel_launch(void* const* d_in, const int* in_sizes, int n_in,
                              void* d_out, int out_size, void* d_ws, size_t ws_size,
                              hipStream_t stream) {
  const float* inp   = (const float*)d_in[0];
  const float* noise = (const float*)d_in[1];
  const float* mu    = (const float*)d_in[2];
  const float* sg    = (const float*)d_in[3];
  const float* lniw  = (const float*)d_in[4];
  const float* lnib  = (const float*)d_in[5];
  const float* lnsw  = (const float*)d_in[6];
  const float* lnsb  = (const float*)d_in[7];
  const float* lnfw  = (const float*)d_in[8];
  const float* lnfb  = (const float*)d_in[9];
  const float* wk    = (const float*)d_in[10];
  const float* bk    = (const float*)d_in[11];
  const float* wq    = (const float*)d_in[12];
  const float* bq    = (const float*)d_in[13];
  const float* wv    = (const float*)d_in[14];
  const float* bv    = (const float*)d_in[15];
  const float* wih   = (const float*)d_in[16];
  const float* bih   = (const float*)d_in[17];
  const float* whh   = (const float*)d_in[18];
  const float* bhh   = (const float*)d_in[19];
  const float* w1    = (const float*)d_in[20];
  const float* b1    = (const float*)d_in[21];
  const float* w2    = (const float*)d_in[22];
  const float* b2    = (const float*)d_in[23];
  float* ws = (float*)d_ws;
  float* slots = ws;                              // 32768
  float* qprep = ws + 32768;                      // 64*528 = 33792
  float* part  = ws + 32768 + 64 * REC;           // 512*528 = 270336
  float* out   = (float*)d_out;
  init_slots<<<64, 512, 0, stream>>>(noise, mu, sg, slots);
  prep_q<<<B_ * K_, 64, 0, stream>>>(slots, lnsw, lnsb, wq, bq, wk, bk, lniw, lnib, qprep);
  for (int it = 0; it < 3; ++it) {
    attn_pass<<<B_ * CHUNKS, 256, 0, stream>>>(inp, qprep, part);
    slot_update<<<B_ * K_, 256, 0, stream>>>(
        part, slots, lniw, lnib, wv, bv, wih, bih, whh, bhh,
        lnfw, lnfb, w1, b1, w2, b2, lnsw, lnsb, wq, bq, wk, bk,
        (it == 2) ? out : slots, qprep, (it < 2) ? 1 : 0);
  }
}

// Round 3
// 318.402 us; speedup vs baseline: 1.1814x; 1.1814x over previous
//
#include <hip/hip_runtime.h>
#include <math.h>

#define B_ 64
#define N_ 16384
#define K_ 8
#define SCALE 0.125f          // 1/sqrt(64)
#define LN_EPS 1e-5f
#define CHUNKS 4
#define ROWS_PER_CHUNK (N_ / CHUNKS)   // 4096
#define TILE 256
#define TILES (ROWS_PER_CHUNK / TILE)  // 16
#define REC 528               // record: 512 Y + 8 S + 8 t1

__device__ __forceinline__ float wsum64(float v) {
#pragma unroll
  for (int m = 1; m < 64; m <<= 1) v += __shfl_xor(v, m);
  return v;
}

// async global->LDS, 16B per lane; LDS dest must be wave-uniform base + lane*16
__device__ __forceinline__ void dma16(const float* g, float* l) {
  __builtin_amdgcn_global_load_lds(
      (const __attribute__((address_space(1))) float*)g,
      (__attribute__((address_space(3))) float*)l, 16, 0, 0);
}

// slots = mu + sigma * noise   (32768 elems)
__global__ void init_slots(const float* __restrict__ noise, const float* __restrict__ mu,
                           const float* __restrict__ sg, float* __restrict__ slots) {
  int i = blockIdx.x * blockDim.x + threadIdx.x;
  int d = i & 63;
  slots[i] = mu[d] + sg[d] * noise[i];
}

// Per (b,kk): q = LN(slots; ln_slots)@wq + bq ; fold through wk and input-LN affine.
__global__ __launch_bounds__(64) void prep_q(
    const float* __restrict__ slots,
    const float* __restrict__ lnsw, const float* __restrict__ lnsb,
    const float* __restrict__ wq, const float* __restrict__ bq,
    const float* __restrict__ wk, const float* __restrict__ bk,
    const float* __restrict__ lniw, const float* __restrict__ lnib,
    float* __restrict__ qprep) {
  const int bk_i = blockIdx.x;            // b*8+kk
  const int b = bk_i >> 3, kk = bk_i & 7;
  const int d = threadIdx.x;
  __shared__ float xs[64], qsh[64], wkl[64 * 65];
  for (int i = 0; i < 64; ++i) wkl[i * 65 + d] = wk[i * 64 + d];
  float s = slots[bk_i * 64 + d];
  float m = wsum64(s) * (1.f / 64.f);
  float df = s - m;
  float var = wsum64(df * df) * (1.f / 64.f);
  float r = 1.f / sqrtf(var + LN_EPS);
  xs[d] = df * r * lnsw[d] + lnsb[d];
  __syncthreads();
  float q = bq[d];
  for (int c = 0; c < 64; ++c) q += xs[c] * wq[c * 64 + d];
  qsh[d] = q;
  __syncthreads();
  float qp = 0.f, c0 = 0.f;
  for (int dd = 0; dd < 64; ++dd) {
    float qd = qsh[dd];
    qp += wkl[d * 65 + dd] * qd;
    c0 += qd * bk[dd];
  }
  float qw = qp * lniw[d] * SCALE;
  float As = wsum64(qw);
  float Bp = wsum64(qp * lnib[d]);
  float Bc = (Bp + c0) * SCALE;
  float* rec = qprep + b * REC;
  rec[d * 8 + kk] = qw;                   // qwT[c][kk]
  if (d == 0) { rec[512 + kk] = As; rec[520 + kk] = Bc; }
}

// Streaming pass: grid = 256 blocks x 512 threads, 1 block/CU.
// Double-buffered 64KB LDS tiles filled by global_load_lds with pre-rotated
// source (swizzle phys_quad = (j+row)&15); counted vmcnt + raw s_barrier keep
// next tile's DMA in flight across barriers.
__global__ __launch_bounds__(512, 2) void attn_pass(
    const float* __restrict__ inp, const float* __restrict__ qprep,
    float* __restrict__ part) {
  __shared__ __align__(16) float xbuf[2][TILE * 64];   // 128 KB
  __shared__ __align__(16) float qwT[512];             // qw[c][kk], per-lane indexed
  __shared__ float2 aw[4][TILE + 4];                   // a*r pairs per row
  __shared__ float redST[128];
  const int tid = threadIdx.x;
  const int b = blockIdx.x >> 2, chunk = blockIdx.x & 3;
  const int w = tid >> 6;
  const float* __restrict__ qp = qprep + b * REC;
  const float* srcbase = inp + ((size_t)b * N_ + (size_t)chunk * ROWS_PER_CHUNK) * 64;
  // stage qwT (phase A indexes it per-lane -> LDS, not s_load)
  qwT[tid] = qp[tid];
  // hoist AsBc into registers: keeps the main loop free of non-DMA vmcnt ops
  float As_[8], Bc_[8];
#pragma unroll
  for (int kq = 0; kq < 8; ++kq) { As_[kq] = qp[512 + kq]; Bc_[kq] = qp[520 + kq]; }
  __syncthreads();                         // qwT visible; drains vmcnt before DMAs
  // prologue: DMA tile 0 into buf 0
  {
    const float* tb = srcbase;
    float* lb = &xbuf[0][0];
#pragma unroll
    for (int r8 = 0; r8 < 8; ++r8) {
      const int R = r8 * 32 + (tid >> 4);
      const int q = tid & 15;
      const int lj = (q - R) & 15;         // inverse swizzle on global source
      dma16(tb + R * 64 + lj * 4, lb + (r8 * 512 + (tid & ~63)) * 4);
    }
  }
  const int h = tid & 1, R = tid >> 1;     // pair-per-row mapping (phase A)
  const int p = (tid & 63) >> 4, dqv = tid & 15;  // phase B mapping
  float Ya[8] = {0,0,0,0,0,0,0,0};
  float sS[8] = {0,0,0,0,0,0,0,0};
  float sT[8] = {0,0,0,0,0,0,0,0};
  for (int t = 0; t < TILES; ++t) {
    const int cur = t & 1;
    __builtin_amdgcn_s_barrier();          // b1: closes B(t-1); frees buf[cur^1] + aw
    if (t + 1 < TILES) {
      const float* tb = srcbase + (size_t)(t + 1) * TILE * 64;
      float* lb = &xbuf[cur ^ 1][0];
#pragma unroll
      for (int r8 = 0; r8 < 8; ++r8) {
        const int Rr = r8 * 32 + (tid >> 4);
        const int q = tid & 15;
        const int lj = (q - Rr) & 15;
        dma16(tb + Rr * 64 + lj * 4, lb + (r8 * 512 + (tid & ~63)) * 4);
      }
      asm volatile("s_waitcnt vmcnt(8)" ::: "memory");   // drain tile t, keep t+1 in flight
    } else {
      asm volatile("s_waitcnt vmcnt(0)" ::: "memory");
    }
    __builtin_amdgcn_sched_barrier(0);
    __builtin_amdgcn_s_barrier();          // b2: buf[cur] ready for all waves
    // ---- phase A: pair (h) per row R; each lane does 32 cols ----
    const float* rowp = &xbuf[cur][R * 64];
    float4 xq[8];
#pragma unroll
    for (int jj = 0; jj < 8; ++jj) {
      const int qph = (h * 8 + jj + R) & 15;             // read-side swizzle
      xq[jj] = *reinterpret_cast<const float4*>(&rowp[qph * 4]);
    }
    float sum = 0.f, sq = 0.f;
    float l[8] = {0,0,0,0,0,0,0,0};
#pragma unroll
    for (int jj = 0; jj < 8; ++jj) {
      float xc[4] = {xq[jj].x, xq[jj].y, xq[jj].z, xq[jj].w};
#pragma unroll
      for (int e = 0; e < 4; ++e) {
        const int c = h * 32 + jj * 4 + e;
        const float v = xc[e];
        sum += v; sq += v * v;
        const float4 qa = *reinterpret_cast<const float4*>(&qwT[c * 8]);
        const float4 qb = *reinterpret_cast<const float4*>(&qwT[c * 8 + 4]);
        l[0] += qa.x * v; l[1] += qa.y * v; l[2] += qa.z * v; l[3] += qa.w * v;
        l[4] += qb.x * v; l[5] += qb.y * v; l[6] += qb.z * v; l[7] += qb.w * v;
      }
    }
#pragma unroll
    for (int kq = 0; kq < 8; ++kq) l[kq] += __shfl_xor(l[kq], 1);
    sum += __shfl_xor(sum, 1);
    sq  += __shfl_xor(sq, 1);
    const float m = sum * (1.f / 64.f);
    const float var = sq * (1.f / 64.f) - m * m;
    const float r = 1.f / sqrtf(var + LN_EPS);
    const float mr = m * r;
    float lmax = -1e30f;
#pragma unroll
    for (int kq = 0; kq < 8; ++kq) {
      l[kq] = r * l[kq] - mr * As_[kq] + Bc_[kq];
      lmax = fmaxf(lmax, l[kq]);
    }
    float es = 0.f;
#pragma unroll
    for (int kq = 0; kq < 8; ++kq) { l[kq] = __expf(l[kq] - lmax); es += l[kq]; }
    const float inv = 1.f / es;
#pragma unroll
    for (int kq = 0; kq < 8; ++kq) {
      l[kq] *= inv;                        // a[kq]
      sS[kq] += l[kq];                     // both lanes of pair -> 0.5x at end
      sT[kq] += l[kq] * mr;
    }
    if (h == 0) {
#pragma unroll
      for (int pp = 0; pp < 4; ++pp) {
        float2 v2; v2.x = l[2 * pp] * r; v2.y = l[2 * pp + 1] * r;
        aw[pp][R] = v2;
      }
    }
    asm volatile("s_waitcnt lgkmcnt(0)" ::: "memory");
    __builtin_amdgcn_s_barrier();          // b3: aw visible
    // ---- phase B: wave w rows w*32..+31; lane (p,dqv): kk=2p,2p+1, d=dqv*4..+3 ----
#pragma unroll 8
    for (int i = 0; i < 32; ++i) {
      const int nl = w * 32 + i;
      const float2 a2 = aw[p][nl];
      const float4 xv = *reinterpret_cast<const float4*>(
          &xbuf[cur][nl * 64 + (((dqv + nl) & 15) << 2)]);
      Ya[0] += a2.x * xv.x; Ya[1] += a2.x * xv.y; Ya[2] += a2.x * xv.z; Ya[3] += a2.x * xv.w;
      Ya[4] += a2.y * xv.x; Ya[5] += a2.y * xv.y; Ya[6] += a2.y * xv.z; Ya[7] += a2.y * xv.w;
    }
  }
  // ---- epilogue ----
#pragma unroll
  for (int kq = 0; kq < 8; ++kq) { sS[kq] = wsum64(sS[kq]); sT[kq] = wsum64(sT[kq]); }
  if ((tid & 63) == 0) {
#pragma unroll
    for (int i = 0; i < 8; ++i) { redST[w * 16 + i] = sS[i]; redST[w * 16 + 8 + i] = sT[i]; }
  }
  float* yr = &xbuf[0][0];                 // last tile read xbuf[1]; xbuf[0] is free
  *reinterpret_cast<float4*>(&yr[tid * 8])     = make_float4(Ya[0], Ya[1], Ya[2], Ya[3]);
  *reinterpret_cast<float4*>(&yr[tid * 8 + 4]) = make_float4(Ya[4], Ya[5], Ya[6], Ya[7]);
  asm volatile("s_waitcnt lgkmcnt(0)" ::: "memory");
  __builtin_amdgcn_s_barrier();
  float* dst = part + (size_t)blockIdx.x * REC;
  {
    const int kq = tid >> 6, dd = tid & 63;
    const int pp = kq >> 1, cc = kq & 1, dqq = dd >> 2, ee = dd & 3;
    float v = 0.f;
#pragma unroll
    for (int ww = 0; ww < 8; ++ww)
      v += yr[(ww * 64 + pp * 16 + dqq) * 8 + cc * 4 + ee];
    dst[tid] = v;
  }
  if (tid < 16)
    dst[512 + tid] = 0.5f * (redST[tid] + redST[16 + tid] + redST[32 + tid] + redST[48 + tid] +
                             redST[64 + tid] + redST[80 + tid] + redST[96 + tid] + redST[112 + tid]);
}

// Fused: partial-reduce -> updates -> GRU -> LN -> MLP -> new slots -> q-prep(next).
__global__ __launch_bounds__(256) void slot_update(
    const float* __restrict__ part, const float* slots_in,
    const float* __restrict__ lniw, const float* __restrict__ lnib,
    const float* __restrict__ wv, const float* __restrict__ bv,
    const float* __restrict__ wih, const float* __restrict__ bih,
    const float* __restrict__ whh, const float* __restrict__ bhh,
    const float* __restrict__ lnfw, const float* __restrict__ lnfb,
    const float* __restrict__ w1, const float* __restrict__ b1,
    const float* __restrict__ w2, const float* __restrict__ b2,
    const float* __restrict__ lnsw, const float* __restrict__ lnsb,
    const float* __restrict__ wq, const float* __restrict__ bq,
    const float* __restrict__ wk, const float* __restrict__ bkv,
    float* slots_out, float* __restrict__ qprep, const int do_prep) {
  const int bk_i = blockIdx.x, b = bk_i >> 3, kk = bk_i & 7;
  const int tid = threadIdx.x, cq = tid >> 6, d = tid & 63;
  const int c0 = cq * 16;
  __shared__ float pA[4][68], pB[4][68], pC[4][68], pD[4][68];
  __shared__ float xsh[64], psh[64], ush[64], hsh[64], snsh[64], qsh[64];
  __shared__ float hid1[2][132];
  const float* pb = part + (size_t)(b * CHUNKS) * REC;
  float S = 0.f, T1 = 0.f;
#pragma unroll
  for (int ch = 0; ch < CHUNKS; ++ch) {
    S += pb[ch * REC + 512 + kk];
    T1 += pb[ch * REC + 520 + kk];
  }
  pA[cq][d] = pb[cq * REC + kk * 64 + d];        // one chunk per cq
  const float prev = slots_in[bk_i * 64 + d];
  if (cq == 0) psh[d] = prev;
  __syncthreads();                               // s1
  if (cq == 0) {
    const float Y = pA[0][d] + pA[1][d] + pA[2][d] + pA[3][d];
    xsh[d] = lniw[d] * (Y - T1) + lnib[d] * S;
  }
  __syncthreads();                               // s2
  {
    float up = 0.f, h0 = 0.f, h1 = 0.f, h2 = 0.f;
    for (int c = c0; c < c0 + 16; ++c) {
      const float xc = xsh[c], pc = psh[c];
      up += wv[c * 64 + d] * xc;
      h0 += pc * whh[c * 192 + d];
      h1 += pc * whh[c * 192 + 64 + d];
      h2 += pc * whh[c * 192 + 128 + d];
    }
    pA[cq][d] = up; pB[cq][d] = h0; pC[cq][d] = h1; pD[cq][d] = h2;
  }
  __syncthreads();                               // s3
  float hh0 = 0.f, hh1 = 0.f, hh2 = 0.f;
  if (cq == 0) {
    ush[d] = S * bv[d] + pA[0][d] + pA[1][d] + pA[2][d] + pA[3][d];
    hh0 = bhh[d] + pB[0][d] + pB[1][d] + pB[2][d] + pB[3][d];
    hh1 = bhh[64 + d] + pC[0][d] + pC[1][d] + pC[2][d] + pC[3][d];
    hh2 = bhh[128 + d] + pD[0][d] + pD[1][d] + pD[2][d] + pD[3][d];
  }
  __syncthreads();                               // s4
  {
    float g0 = 0.f, g1 = 0.f, g2 = 0.f;
    for (int c = c0; c < c0 + 16; ++c) {
      const float uc = ush[c];
      g0 += uc * wih[c * 192 + d];
      g1 += uc * wih[c * 192 + 64 + d];
      g2 += uc * wih[c * 192 + 128 + d];
    }
    pA[cq][d] = g0; pB[cq][d] = g1; pC[cq][d] = g2;
  }
  __syncthreads();                               // s5
  if (cq == 0) {
    const float gi0 = bih[d] + pA[0][d] + pA[1][d] + pA[2][d] + pA[3][d];
    const float gi1 = bih[64 + d] + pB[0][d] + pB[1][d] + pB[2][d] + pB[3][d];
    const float gi2 = bih[128 + d] + pC[0][d] + pC[1][d] + pC[2][d] + pC[3][d];
    const float rg = 1.f / (1.f + __expf(-(gi0 + hh0)));
    const float zg = 1.f / (1.f + __expf(-(gi1 + hh1)));
    const float ng = tanhf(gi2 + rg * hh2);
    const float sn = (1.f - zg) * ng + zg * prev;
    const float mm = wsum64(sn) * (1.f / 64.f);
    const float df = sn - mm;
    const float vv = wsum64(df * df) * (1.f / 64.f);
    const float rr = 1.f / sqrtf(vv + LN_EPS);
    snsh[d] = sn;
    hsh[d] = df * rr * lnfw[d] + lnfb[d];
  }
  __syncthreads();                               // s6
  {
    const int j = tid & 127, ch2 = tid >> 7;
    float a = 0.f;
    for (int c = ch2 * 32; c < ch2 * 32 + 32; ++c) a += hsh[c] * w1[c * 128 + j];
    hid1[ch2][j] = a;
  }
  __syncthreads();                               // s7
  {
    float o = 0.f;
    for (int j2 = cq * 32; j2 < cq * 32 + 32; ++j2) {
      const float hv = fmaxf(hid1[0][j2] + hid1[1][j2] + b1[j2], 0.f);
      o += hv * w2[j2 * 64 + d];
    }
    pA[cq][d] = o;
  }
  __syncthreads();                               // s8
  float news = 0.f;
  if (cq == 0) {
    news = snsh[d] + b2[d] + pA[0][d] + pA[1][d] + pA[2][d] + pA[3][d];
    slots_out[bk_i * 64 + d] = news;
  }
  if (!do_prep) return;
  // ---- fused q-prep for next iteration ----
  if (cq == 0) {
    const float mm = wsum64(news) * (1.f / 64.f);
    const float df = news - mm;
    const float vv = wsum64(df * df) * (1.f / 64.f);
    const float rr = 1.f / sqrtf(vv + LN_EPS);
    xsh[d] = df * rr * lnsw[d] + lnsb[d];
  }
  __syncthreads();                               // s9
  {
    float qpt = 0.f;
    for (int c = c0; c < c0 + 16; ++c) qpt += xsh[c] * wq[c * 64 + d];
    pB[cq][d] = qpt;
  }
  __syncthreads();                               // s10
  if (cq == 0) qsh[d] = bq[d] + pB[0][d] + pB[1][d] + pB[2][d] + pB[3][d];
  __syncthreads();                               // s11
  {
    float qq = 0.f;
    for (int dd2 = c0; dd2 < c0 + 16; ++dd2) qq += wk[d * 64 + dd2] * qsh[dd2];
    pC[cq][d] = qq;
  }
  __syncthreads();                               // s12
  if (cq == 0) {
    const float qpv = pC[0][d] + pC[1][d] + pC[2][d] + pC[3][d];
    const float c0v = wsum64(qsh[d] * bkv[d]);
    const float qw = qpv * lniw[d] * SCALE;
    const float As = wsum64(qw);
    const float Bp = wsum64(qpv * lnib[d]);
    const float Bc = (Bp + c0v) * SCALE;
    float* rec = qprep + b * REC;
    rec[d * 8 + kk] = qw;
    if (d == 0) { rec[512 + kk] = As; rec[520 + kk] = Bc; }
  }
}

extern "C" void kernel_launch(void* const* d_in, const int* in_sizes, int n_in,
                              void* d_out, int out_size, void* d_ws, size_t ws_size,
                              hipStream_t stream) {
  const float* inp   = (const float*)d_in[0];
  const float* noise = (const float*)d_in[1];
  const float* mu    = (const float*)d_in[2];
  const float* sg    = (const float*)d_in[3];
  const float* lniw  = (const float*)d_in[4];
  const float* lnib  = (const float*)d_in[5];
  const float* lnsw  = (const float*)d_in[6];
  const float* lnsb  = (const float*)d_in[7];
  const float* lnfw  = (const float*)d_in[8];
  const float* lnfb  = (const float*)d_in[9];
  const float* wk    = (const float*)d_in[10];
  const float* bk    = (const float*)d_in[11];
  const float* wq    = (const float*)d_in[12];
  const float* bq    = (const float*)d_in[13];
  const float* wv    = (const float*)d_in[14];
  const float* bv    = (const float*)d_in[15];
  const float* wih   = (const float*)d_in[16];
  const float* bih   = (const float*)d_in[17];
  const float* whh   = (const float*)d_in[18];
  const float* bhh   = (const float*)d_in[19];
  const float* w1    = (const float*)d_in[20];
  const float* b1    = (const float*)d_in[21];
  const float* w2    = (const float*)d_in[22];
  const float* b2    = (const float*)d_in[23];
  float* ws = (float*)d_ws;
  float* slots = ws;                              // 32768
  float* qprep = ws + 32768;                      // 64*528 = 33792
  float* part  = ws + 32768 + 64 * REC;           // 256*528 = 135168
  float* out   = (float*)d_out;
  init_slots<<<64, 512, 0, stream>>>(noise, mu, sg, slots);
  prep_q<<<B_ * K_, 64, 0, stream>>>(slots, lnsw, lnsb, wq, bq, wk, bk, lniw, lnib, qprep);
  for (int it = 0; it < 3; ++it) {
    attn_pass<<<B_ * CHUNKS, 512, 0, stream>>>(inp, qprep, part);
    slot_update<<<B_ * K_, 256, 0, stream>>>(
        part, slots, lniw, lnib, wv, bv, wih, bih, whh, bhh,
        lnfw, lnfb, w1, b1, w2, b2, lnsw, lnsb, wq, bq, wk, bk,
        (it == 2) ? out : slots, qprep, (it < 2) ? 1 : 0);
  }
}